// Round 5
// baseline (331.685 us; speedup 1.0000x reference)
//
#include <hip/hip_runtime.h>
#include <stdint.h>

static constexpr int NN  = 50000;
static constexpr int EE  = 800000;
static constexpr int FIN = 256;
static constexpr int HID = 128;
static constexpr int SZ_LOG = 8;                       // 256 nodes per bucket
static constexpr int NBUCK  = (NN + 255) >> SZ_LOG;    // 196
static constexpr int CH     = 2048;                    // edges per block (hist/scatter)
static constexpr int NCBLK  = (EE + CH - 1) / CH;      // 391

typedef __attribute__((ext_vector_type(8))) short  short8;
typedef __attribute__((ext_vector_type(8))) __bf16 bf16x8;
typedef __attribute__((ext_vector_type(4))) float  f32x4;
typedef uint16_t u16;

__device__ __forceinline__ u16 f2bf(float f) {
  union { float f; uint32_t u; } v; v.f = f;
  return (u16)((v.u + 0x7fffu + ((v.u >> 16) & 1u)) >> 16);  // RNE
}
__device__ __forceinline__ float bflo(uint32_t u) {
  union { uint32_t u; float f; } v; v.u = u << 16; return v.f;
}
__device__ __forceinline__ float bfhi(uint32_t u) {
  union { uint32_t u; float f; } v; v.u = u & 0xffff0000u; return v.f;
}
__device__ __forceinline__ void accum8(float a[8], uint4 v, float wn) {
  a[0] += wn * bflo(v.x); a[1] += wn * bfhi(v.x);
  a[2] += wn * bflo(v.y); a[3] += wn * bfhi(v.y);
  a[4] += wn * bflo(v.z); a[5] += wn * bfhi(v.z);
  a[6] += wn * bflo(v.w); a[7] += wn * bfhi(v.w);
}

// ---------------- bucketed CSR build ----------------
// A: bucket histogram, LDS-aggregated
__global__ __launch_bounds__(256) void k_bhist(const int* __restrict__ dst, int* __restrict__ bcnt, int e) {
  __shared__ int lc[NBUCK];
  int tid = threadIdx.x;
  for (int i = tid; i < NBUCK; i += 256) lc[i] = 0;
  __syncthreads();
  int base = blockIdx.x * CH;
#pragma unroll
  for (int j = 0; j < 8; ++j) {
    int i = base + j * 256 + tid;
    if (i < e) atomicAdd(&lc[dst[i] >> SZ_LOG], 1);
  }
  __syncthreads();
  for (int i = tid; i < NBUCK; i += 256) if (lc[i]) atomicAdd(&bcnt[i], lc[i]);
}

// B: scan 196 bucket counts (1 block)
__global__ __launch_bounds__(256) void k_bscan(const int* __restrict__ bcnt, int* __restrict__ boff,
                                               int* __restrict__ bcur, int* __restrict__ off) {
  __shared__ int buf[256];
  int tid = threadIdx.x;
  int v = (tid < NBUCK) ? bcnt[tid] : 0;
  buf[tid] = v;
  __syncthreads();
  for (int o = 1; o < 256; o <<= 1) {
    int t = (tid >= o) ? buf[tid - o] : 0;
    __syncthreads();
    buf[tid] += t;
    __syncthreads();
  }
  int ex = buf[tid] - v;
  if (tid < NBUCK) { boff[tid] = ex; bcur[tid] = ex; }
  if (tid == NBUCK - 1) boff[NBUCK] = ex + v;   // == EE
  if (tid == 0) off[NN] = EE;
}

// C: scatter (s,d) into bucket-contiguous storage; per-block chunk reservation
__global__ __launch_bounds__(256) void k_bscatter(const int* __restrict__ src, const int* __restrict__ dst,
                                                  int* __restrict__ bcur, int2* __restrict__ ebuck, int e) {
  __shared__ int lc[NBUCK];
  __shared__ int lb[NBUCK];
  int tid = threadIdx.x;
  for (int i = tid; i < NBUCK; i += 256) lc[i] = 0;
  __syncthreads();
  int base = blockIdx.x * CH;
  int sj[8], dj[8], rj[8];
#pragma unroll
  for (int j = 0; j < 8; ++j) {
    int i = base + j * 256 + tid;
    if (i < e) {
      sj[j] = src[i]; dj[j] = dst[i];
      rj[j] = atomicAdd(&lc[dj[j] >> SZ_LOG], 1);
    }
  }
  __syncthreads();
  for (int i = tid; i < NBUCK; i += 256) { int c = lc[i]; if (c) lb[i] = atomicAdd(&bcur[i], c); }
  __syncthreads();
#pragma unroll
  for (int j = 0; j < 8; ++j) {
    int i = base + j * 256 + tid;
    if (i < e) ebuck[lb[dj[j] >> SZ_LOG] + rj[j]] = make_int2(sj[j], dj[j]);
  }
}

// D: per-bucket node counts -> off (via LDS scan) + dinv
__global__ __launch_bounds__(256) void k_ncount(const int2* __restrict__ ebuck, const int* __restrict__ boff,
                                                int* __restrict__ off, float* __restrict__ dinv) {
  __shared__ int nc[256];
  __shared__ int sc[256];
  int b = blockIdx.x, tid = threadIdx.x;
  nc[tid] = 0;
  __syncthreads();
  int j0 = boff[b], j1 = boff[b + 1];
  for (int j = j0 + tid; j < j1; j += 256) atomicAdd(&nc[ebuck[j].y & 255], 1);
  __syncthreads();
  int v = nc[tid];
  sc[tid] = v;
  __syncthreads();
  for (int o = 1; o < 256; o <<= 1) {
    int t = (tid >= o) ? sc[tid - o] : 0;
    __syncthreads();
    sc[tid] += t;
    __syncthreads();
  }
  int node = (b << SZ_LOG) + tid;
  if (node < NN) {
    off[node]  = j0 + sc[tid] - v;
    dinv[node] = rsqrtf((float)v + 2.0f);   // improved=True self-loop weight 2.0
  }
}

// F: per-bucket fill of final CSR records; LDS cursors
__global__ __launch_bounds__(256) void k_fill2(const int2* __restrict__ ebuck, const int* __restrict__ boff,
                                               const int* __restrict__ off, const float* __restrict__ dinv,
                                               int2* __restrict__ edges) {
  __shared__ int   lcur[256];
  __shared__ float ldv[256];
  int b = blockIdx.x, tid = threadIdx.x;
  int node = (b << SZ_LOG) + tid;
  lcur[tid] = (node < NN) ? off[node]  : 0;
  ldv[tid]  = (node < NN) ? dinv[node] : 0.f;
  __syncthreads();
  int j0 = boff[b], j1 = boff[b + 1];
  for (int j = j0 + tid; j < j1; j += 256) {
    int2 e = ebuck[j];
    int loc = e.y & 255;
    int pos = atomicAdd(&lcur[loc], 1);
    edges[pos] = make_int2(e.x, __float_as_int(dinv[e.x] * ldv[loc]));
  }
}

// ---------------- weight convert (all four), [K][128] f32 -> tiled bf16 [K/32][128][32] ----
__global__ void k_wconv_all(const float* __restrict__ W1, const float* __restrict__ W2,
                            const float* __restrict__ We, const float* __restrict__ Wf,
                            u16* __restrict__ T1, u16* __restrict__ T2,
                            u16* __restrict__ T3, u16* __restrict__ T4) {
  int i = blockIdx.x * 256 + threadIdx.x;   // 0 .. 81920
  const float* W; u16* o;
  if (i < 32768)      { W = W1; o = T1; }
  else if (i < 49152) { W = W2; o = T2; i -= 32768; }
  else if (i < 65536) { W = We; o = T3; i -= 49152; }
  else                { W = Wf; o = T4; i -= 65536; }
  int k = i >> 7, c = i & 127;
  o[(size_t)((k >> 5) * 128 + c) * 32 + (k & 31)] = f2bf(W[i]);
}

// ---------------- GEMM: [M,K] @ [K,128] -> [M,128], bf16 MFMA, 2-phase dbuf ----------------
template<int AFLOAT, int EPI>
__global__ __launch_bounds__(256) void k_gemm(const float* __restrict__ Af, const u16* __restrict__ Ah,
                                              const u16* __restrict__ Wt, const float* __restrict__ bias,
                                              u16* __restrict__ gout, float* __restrict__ fout,
                                              int M, int K) {
  __shared__ u16 Ash[2][64 * 40];
  __shared__ u16 Bsh[2][128 * 40];
  const int tid  = threadIdx.x;
  const int lane = tid & 63;
  const int w    = tid >> 6;
  const int row0 = blockIdx.x * 64;
  f32x4 acc[8];
#pragma unroll
  for (int t = 0; t < 8; ++t) acc[t] = (f32x4){0.f, 0.f, 0.f, 0.f};

  const int nk = K >> 5;
  const int r = tid >> 2, kg = tid & 3;
  const int grow_a = row0 + r;
  const bool arow_ok = (grow_a < M);

  float  fa[8];        // AFLOAT staging regs
  uint4  ua;           // !AFLOAT staging reg
  uint4  vb[2];        // B staging regs

  // ---- load helpers (registers only) ----
  auto loadA = [&](int kb) {
    int k0 = kb * 32 + kg * 8;
    if (AFLOAT) {
      if (arow_ok) {
        const float* p = Af + (size_t)grow_a * K + k0;
        float4 x0 = *(const float4*)(p);
        float4 x1 = *(const float4*)(p + 4);
        fa[0] = x0.x; fa[1] = x0.y; fa[2] = x0.z; fa[3] = x0.w;
        fa[4] = x1.x; fa[5] = x1.y; fa[6] = x1.z; fa[7] = x1.w;
      } else {
#pragma unroll
        for (int i = 0; i < 8; ++i) fa[i] = 0.f;
      }
    } else {
      if (arow_ok) ua = *(const uint4*)(Ah + (size_t)grow_a * K + kb * 32 + kg * 8);
      else ua = make_uint4(0, 0, 0, 0);
    }
  };
  auto loadB = [&](int kb) {
    const u16* wsrc = Wt + (size_t)kb * 4096;
#pragma unroll
    for (int j = 0; j < 2; ++j) vb[j] = *(const uint4*)(wsrc + (tid * 2 + j) * 8);
  };
  auto storeA = [&](int buf) {
    if (AFLOAT) {
      alignas(16) u16 v[8];
#pragma unroll
      for (int i = 0; i < 8; ++i) v[i] = f2bf(fa[i]);
      *(uint4*)&Ash[buf][r * 40 + kg * 8] = *(const uint4*)v;
    } else {
      *(uint4*)&Ash[buf][r * 40 + kg * 8] = ua;
    }
  };
  auto storeB = [&](int buf) {
#pragma unroll
    for (int j = 0; j < 2; ++j) {
      int chunk = tid * 2 + j;
      Bsh[buf][(chunk >> 2) * 40 + ((chunk & 3) << 3)] = 0;  // placeholder overwritten below
      *(uint4*)&Bsh[buf][(chunk >> 2) * 40 + ((chunk & 3) << 3)] = vb[j];
    }
  };

  // prologue: stage tile 0
  loadA(0); loadB(0);
  storeA(0); storeB(0);
  __syncthreads();

  const int rl = lane & 15, kq = lane >> 4;
  for (int kb = 0; kb < nk; ++kb) {
    const int cur = kb & 1;
    const bool more = (kb + 1 < nk);
    if (more) { loadA(kb + 1); loadB(kb + 1); }   // issue-early: HBM latency hides under MFMA
    short8 af = *(const short8*)&Ash[cur][(w * 16 + rl) * 40 + kq * 8];
#pragma unroll
    for (int t = 0; t < 8; ++t) {
      short8 bf = *(const short8*)&Bsh[cur][(t * 16 + rl) * 40 + kq * 8];
      acc[t] = __builtin_amdgcn_mfma_f32_16x16x32_bf16(
          __builtin_bit_cast(bf16x8, af), __builtin_bit_cast(bf16x8, bf), acc[t], 0, 0, 0);
    }
    if (more) {
      storeA(cur ^ 1); storeB(cur ^ 1);           // write the other buffer
      __syncthreads();                            // one barrier per K-step
    }
  }

  // epilogue: C/D layout col=lane&15, row=(lane>>4)*4+i
  const int rq = lane >> 4;
#pragma unroll
  for (int t = 0; t < 8; ++t) {
    int col = t * 16 + rl;
#pragma unroll
    for (int i = 0; i < 4; ++i) {
      int grow = row0 + w * 16 + rq * 4 + i;
      if (grow < M) {
        if (EPI == 0) {
          gout[(size_t)grow * HID + col] = f2bf(acc[t][i]);
        } else {
          float vv = acc[t][i] + bias[col];
          fout[(size_t)grow * HID + col] = 1.0f / (1.0f + __expf(-vv));
        }
      }
    }
  }
}

// ---------------- aggregation: one wave per dst node, 4 groups x 16 lanes, unroll x4 ----------------
template<int RELU>
__global__ __launch_bounds__(256) void k_agg(const u16* __restrict__ h, u16* __restrict__ g,
                                             const float* __restrict__ bias, const float* __restrict__ dinv,
                                             const int* __restrict__ off, const int2* __restrict__ edges,
                                             int n) {
  int wave = blockIdx.x * 4 + (threadIdx.x >> 6);
  int lane = threadIdx.x & 63;
  if (wave >= n) return;
  const int d  = wave;
  const int gr = lane >> 4;
  const int t  = lane & 15;
  const int c  = t << 3;
  float a[8];
#pragma unroll
  for (int i = 0; i < 8; ++i) a[i] = 0.f;

  int j  = off[d] + gr;
  const int j1 = off[d + 1];
  // unroll x4 per group: 4 independent edge->gather chains, 16 gathers in flight per wave
  for (; j + 12 < j1; j += 16) {
    int2 e0 = edges[j], e1 = edges[j + 4], e2 = edges[j + 8], e3 = edges[j + 12];
    uint4 v0 = *(const uint4*)(h + (size_t)e0.x * HID + c);
    uint4 v1 = *(const uint4*)(h + (size_t)e1.x * HID + c);
    uint4 v2 = *(const uint4*)(h + (size_t)e2.x * HID + c);
    uint4 v3 = *(const uint4*)(h + (size_t)e3.x * HID + c);
    accum8(a, v0, __int_as_float(e0.y));
    accum8(a, v1, __int_as_float(e1.y));
    accum8(a, v2, __int_as_float(e2.y));
    accum8(a, v3, __int_as_float(e3.y));
  }
  for (; j + 4 < j1; j += 8) {
    int2 e0 = edges[j], e1 = edges[j + 4];
    uint4 v0 = *(const uint4*)(h + (size_t)e0.x * HID + c);
    uint4 v1 = *(const uint4*)(h + (size_t)e1.x * HID + c);
    accum8(a, v0, __int_as_float(e0.y));
    accum8(a, v1, __int_as_float(e1.y));
  }
  for (; j < j1; j += 4) {
    int2 e0 = edges[j];
    uint4 v0 = *(const uint4*)(h + (size_t)e0.x * HID + c);
    accum8(a, v0, __int_as_float(e0.y));
  }
#pragma unroll
  for (int i = 0; i < 8; ++i) {
    a[i] += __shfl_xor(a[i], 16);
    a[i] += __shfl_xor(a[i], 32);
  }
  float di = dinv[d];
  float sl = 2.0f * di * di;
  uint4 sv = *(const uint4*)(h + (size_t)d * HID + c);
  const float4 bv0 = *(const float4*)(bias + c);
  const float4 bv1 = *(const float4*)(bias + c + 4);
  a[0] += sl * bflo(sv.x) + bv0.x; a[1] += sl * bfhi(sv.x) + bv0.y;
  a[2] += sl * bflo(sv.y) + bv0.z; a[3] += sl * bfhi(sv.y) + bv0.w;
  a[4] += sl * bflo(sv.z) + bv1.x; a[5] += sl * bfhi(sv.z) + bv1.y;
  a[6] += sl * bflo(sv.w) + bv1.z; a[7] += sl * bfhi(sv.w) + bv1.w;
  if (RELU) {
#pragma unroll
    for (int i = 0; i < 8; ++i) a[i] = fmaxf(a[i], 0.f);
  }
  if (gr == 0) {
    uint4 o;
    o.x = (uint32_t)f2bf(a[0]) | ((uint32_t)f2bf(a[1]) << 16);
    o.y = (uint32_t)f2bf(a[2]) | ((uint32_t)f2bf(a[3]) << 16);
    o.z = (uint32_t)f2bf(a[4]) | ((uint32_t)f2bf(a[5]) << 16);
    o.w = (uint32_t)f2bf(a[6]) | ((uint32_t)f2bf(a[7]) << 16);
    *(uint4*)(g + (size_t)d * HID + c) = o;
  }
}

extern "C" void kernel_launch(void* const* d_in, const int* in_sizes, int n_in,
                              void* d_out, int out_size, void* d_ws, size_t ws_size,
                              hipStream_t stream) {
  const float* x   = (const float*)d_in[0];
  const int*   ei  = (const int*)d_in[1];        // [2, E] int32
  const float* W1  = (const float*)d_in[2];
  const float* b1  = (const float*)d_in[3];
  const float* W2  = (const float*)d_in[4];
  const float* b2  = (const float*)d_in[5];
  const float* We  = (const float*)d_in[6];
  const float* be  = (const float*)d_in[7];
  const float* Wf  = (const float*)d_in[8];
  const float* bfv = (const float*)d_in[9];
  float* out = (float*)d_out;

  const int* src = ei;
  const int* dst = ei + EE;

  char* p = (char*)d_ws;
  auto take = [&](size_t bytes) { char* r = p; p += (bytes + 255) & ~(size_t)255; return r; };
  int*   bcnt  = (int*)take((size_t)NBUCK * 4);
  int*   boff  = (int*)take((size_t)(NBUCK + 1) * 4);
  int*   bcur  = (int*)take((size_t)NBUCK * 4);
  int*   off   = (int*)take((size_t)(NN + 1) * 4);
  float* dinv  = (float*)take((size_t)NN * 4);
  int2*  edges = (int2*)take((size_t)EE * 8);
  u16*   hA    = (u16*)take((size_t)NN * HID * 2);
  u16*   hB    = (u16*)take((size_t)NN * HID * 2);
  u16*   Wt1   = (u16*)take((size_t)FIN * HID * 2);
  u16*   Wt2   = (u16*)take((size_t)HID * HID * 2);
  u16*   Wt3   = (u16*)take((size_t)HID * HID * 2);
  u16*   Wt4   = (u16*)take((size_t)HID * HID * 2);
  // ebuck (6.4MB) aliases hB (12.8MB): ebuck is dead before agg1 writes hB.
  int2*  ebuck = (int2*)hB;

  // bucketed CSR build
  hipMemsetAsync(bcnt, 0, (size_t)NBUCK * 4, stream);
  k_bhist<<<NCBLK, 256, 0, stream>>>(dst, bcnt, EE);
  k_bscan<<<1, 256, 0, stream>>>(bcnt, boff, bcur, off);
  k_bscatter<<<NCBLK, 256, 0, stream>>>(src, dst, bcur, ebuck, EE);
  k_ncount<<<NBUCK, 256, 0, stream>>>(ebuck, boff, off, dinv);
  k_fill2<<<NBUCK, 256, 0, stream>>>(ebuck, boff, off, dinv, edges);

  // weights -> tiled bf16 (single launch)
  k_wconv_all<<<(81920 + 255) / 256, 256, 0, stream>>>(W1, W2, We, Wf, Wt1, Wt2, Wt3, Wt4);

  const int gemm_grid = (NN + 63) / 64;
  const int agg_grid  = (NN + 3) / 4;

  // layer 1: h = x@W1 ; g = relu(Agg(h) + b1)
  k_gemm<1, 0><<<gemm_grid, 256, 0, stream>>>(x, nullptr, Wt1, nullptr, hA, nullptr, NN, FIN);
  k_agg<1><<<agg_grid, 256, 0, stream>>>(hA, hB, b1, dinv, off, edges, NN);
  // layer 2
  k_gemm<0, 0><<<gemm_grid, 256, 0, stream>>>(nullptr, hB, Wt2, nullptr, hA, nullptr, NN, HID);
  k_agg<1><<<agg_grid, 256, 0, stream>>>(hA, hB, b2, dinv, off, edges, NN);
  // layer 3 (no relu)
  k_gemm<0, 0><<<gemm_grid, 256, 0, stream>>>(nullptr, hB, Wt3, nullptr, hA, nullptr, NN, HID);
  k_agg<0><<<agg_grid, 256, 0, stream>>>(hA, hB, be, dinv, off, edges, NN);
  // final dense + sigmoid
  k_gemm<0, 1><<<gemm_grid, 256, 0, stream>>>(nullptr, hB, Wt4, bfv, nullptr, out, NN, HID);
}

// Round 7
// 293.669 us; speedup vs baseline: 1.1295x; 1.1295x over previous
//
#include <hip/hip_runtime.h>
#include <stdint.h>

static constexpr int NN  = 50000;
static constexpr int EE  = 800000;
static constexpr int FIN = 256;
static constexpr int HID = 128;
static constexpr int SZ_LOG = 8;                       // 256 nodes per bucket
static constexpr int NBUCK  = (NN + 255) >> SZ_LOG;    // 196
static constexpr int CH     = 2048;                    // edges per block (hist/scatter)
static constexpr int NCBLK  = (EE + CH - 1) / CH;      // 391

typedef __attribute__((ext_vector_type(8))) short  short8;
typedef __attribute__((ext_vector_type(8))) __bf16 bf16x8;
typedef __attribute__((ext_vector_type(4))) float  f32x4;
typedef uint16_t u16;

__device__ __forceinline__ u16 f2bf(float f) {
  union { float f; uint32_t u; } v; v.f = f;
  return (u16)((v.u + 0x7fffu + ((v.u >> 16) & 1u)) >> 16);  // RNE
}
__device__ __forceinline__ float bflo(uint32_t u) {
  union { uint32_t u; float f; } v; v.u = u << 16; return v.f;
}
__device__ __forceinline__ float bfhi(uint32_t u) {
  union { uint32_t u; float f; } v; v.u = u & 0xffff0000u; return v.f;
}
__device__ __forceinline__ void add8(float a[8], uint4 v) {
  a[0] += bflo(v.x); a[1] += bfhi(v.x);
  a[2] += bflo(v.y); a[3] += bfhi(v.y);
  a[4] += bflo(v.z); a[5] += bfhi(v.z);
  a[6] += bflo(v.w); a[7] += bfhi(v.w);
}

// ---------------- bucketed CSR build ----------------
// A: bucket histogram, LDS-aggregated
__global__ __launch_bounds__(256) void k_bhist(const int* __restrict__ dst, int* __restrict__ bcnt, int e) {
  __shared__ int lc[NBUCK];
  int tid = threadIdx.x;
  for (int i = tid; i < NBUCK; i += 256) lc[i] = 0;
  __syncthreads();
  int base = blockIdx.x * CH;
#pragma unroll
  for (int j = 0; j < 8; ++j) {
    int i = base + j * 256 + tid;
    if (i < e) atomicAdd(&lc[dst[i] >> SZ_LOG], 1);
  }
  __syncthreads();
  for (int i = tid; i < NBUCK; i += 256) if (lc[i]) atomicAdd(&bcnt[i], lc[i]);
}

// B: scan 196 bucket counts (1 block)
__global__ __launch_bounds__(256) void k_bscan(const int* __restrict__ bcnt, int* __restrict__ boff,
                                               int* __restrict__ bcur, int* __restrict__ off) {
  __shared__ int buf[256];
  int tid = threadIdx.x;
  int v = (tid < NBUCK) ? bcnt[tid] : 0;
  buf[tid] = v;
  __syncthreads();
  for (int o = 1; o < 256; o <<= 1) {
    int t = (tid >= o) ? buf[tid - o] : 0;
    __syncthreads();
    buf[tid] += t;
    __syncthreads();
  }
  int ex = buf[tid] - v;
  if (tid < NBUCK) { boff[tid] = ex; bcur[tid] = ex; }
  if (tid == NBUCK - 1) boff[NBUCK] = ex + v;   // == EE
  if (tid == 0) off[NN] = EE;
}

// C: scatter packed (s<<8 | d&255) into bucket-contiguous storage (s < 2^24 so it fits)
__global__ __launch_bounds__(256) void k_bscatter(const int* __restrict__ src, const int* __restrict__ dst,
                                                  int* __restrict__ bcur, int* __restrict__ ebuck, int e) {
  __shared__ int lc[NBUCK];
  __shared__ int lb[NBUCK];
  int tid = threadIdx.x;
  for (int i = tid; i < NBUCK; i += 256) lc[i] = 0;
  __syncthreads();
  int base = blockIdx.x * CH;
  int sj[8], dj[8], rj[8];
#pragma unroll
  for (int j = 0; j < 8; ++j) {
    int i = base + j * 256 + tid;
    if (i < e) {
      sj[j] = src[i]; dj[j] = dst[i];
      rj[j] = atomicAdd(&lc[dj[j] >> SZ_LOG], 1);
    }
  }
  __syncthreads();
  for (int i = tid; i < NBUCK; i += 256) { int c = lc[i]; if (c) lb[i] = atomicAdd(&bcur[i], c); }
  __syncthreads();
#pragma unroll
  for (int j = 0; j < 8; ++j) {
    int i = base + j * 256 + tid;
    if (i < e) ebuck[lb[dj[j] >> SZ_LOG] + rj[j]] = (sj[j] << 8) | (dj[j] & 255);
  }
}

// D: per-bucket node counts -> off (via LDS scan) + dinv
__global__ __launch_bounds__(256) void k_ncount(const int* __restrict__ ebuck, const int* __restrict__ boff,
                                                int* __restrict__ off, float* __restrict__ dinv) {
  __shared__ int nc[256];
  __shared__ int sc[256];
  int b = blockIdx.x, tid = threadIdx.x;
  nc[tid] = 0;
  __syncthreads();
  int j0 = boff[b], j1 = boff[b + 1];
  for (int j = j0 + tid; j < j1; j += 256) atomicAdd(&nc[ebuck[j] & 255], 1);
  __syncthreads();
  int v = nc[tid];
  sc[tid] = v;
  __syncthreads();
  for (int o = 1; o < 256; o <<= 1) {
    int t = (tid >= o) ? sc[tid - o] : 0;
    __syncthreads();
    sc[tid] += t;
    __syncthreads();
  }
  int node = (b << SZ_LOG) + tid;
  if (node < NN) {
    off[node]  = j0 + sc[tid] - v;
    dinv[node] = rsqrtf((float)v + 2.0f);   // improved=True self-loop weight 2.0
  }
}

// F: per-bucket fill of final CSR src list; LDS cursors, no dinv gathers
__global__ __launch_bounds__(256) void k_fill2(const int* __restrict__ ebuck, const int* __restrict__ boff,
                                               const int* __restrict__ off, int* __restrict__ edges) {
  __shared__ int lcur[256];
  int b = blockIdx.x, tid = threadIdx.x;
  int node = (b << SZ_LOG) + tid;
  lcur[tid] = (node < NN) ? off[node] : 0;
  __syncthreads();
  int j0 = boff[b], j1 = boff[b + 1];
  for (int j = j0 + tid; j < j1; j += 256) {
    int e = ebuck[j];
    int pos = atomicAdd(&lcur[e & 255], 1);
    edges[pos] = e >> 8;                     // src node id
  }
}

// ---------------- weight convert (all four), [K][128] f32 -> tiled bf16 [K/32][128][32] ----
__global__ void k_wconv_all(const float* __restrict__ W1, const float* __restrict__ W2,
                            const float* __restrict__ We, const float* __restrict__ Wf,
                            u16* __restrict__ T1, u16* __restrict__ T2,
                            u16* __restrict__ T3, u16* __restrict__ T4) {
  int i = blockIdx.x * 256 + threadIdx.x;   // 0 .. 81920
  const float* W; u16* o;
  if (i < 32768)      { W = W1; o = T1; }
  else if (i < 49152) { W = W2; o = T2; i -= 32768; }
  else if (i < 65536) { W = We; o = T3; i -= 49152; }
  else                { W = Wf; o = T4; i -= 65536; }
  int k = i >> 7, c = i & 127;
  o[(size_t)((k >> 5) * 128 + c) * 32 + (k & 31)] = f2bf(W[i]);
}

// ---------------- GEMM: [M,K] @ [K,128] -> [M,128], bf16 MFMA (R3-proven structure) ----------
// EPI=0: store h' = dinv[row]*acc as bf16.  EPI=1: bias+sigmoid, store f32.
template<int AFLOAT, int EPI>
__global__ __launch_bounds__(256) void k_gemm(const float* __restrict__ Af, const u16* __restrict__ Ah,
                                              const u16* __restrict__ Wt, const float* __restrict__ bias,
                                              const float* __restrict__ dinv,
                                              u16* __restrict__ gout, float* __restrict__ fout,
                                              int M, int K) {
  __shared__ u16 Ash[64 * 40];
  __shared__ u16 Bsh[128 * 40];
  const int tid  = threadIdx.x;
  const int lane = tid & 63;
  const int w    = tid >> 6;
  const int row0 = blockIdx.x * 64;
  f32x4 acc[8];
#pragma unroll
  for (int t = 0; t < 8; ++t) acc[t] = (f32x4){0.f, 0.f, 0.f, 0.f};

  const int nk = K >> 5;
  const int r = tid >> 2, kg = tid & 3;
  const int grow_a = row0 + r;
  for (int kb = 0; kb < nk; ++kb) {
    {
      int k0 = kb * 32 + kg * 8;
      alignas(16) u16 v[8];
      if (grow_a < M) {
        if (AFLOAT) {
          const float* p = Af + (size_t)grow_a * K + k0;
          float4 x0 = *(const float4*)(p);
          float4 x1 = *(const float4*)(p + 4);
          v[0] = f2bf(x0.x); v[1] = f2bf(x0.y); v[2] = f2bf(x0.z); v[3] = f2bf(x0.w);
          v[4] = f2bf(x1.x); v[5] = f2bf(x1.y); v[6] = f2bf(x1.z); v[7] = f2bf(x1.w);
        } else {
          *(uint4*)v = *(const uint4*)(Ah + (size_t)grow_a * K + k0);
        }
      } else {
#pragma unroll
        for (int i = 0; i < 8; ++i) v[i] = 0;
      }
      *(uint4*)&Ash[r * 40 + kg * 8] = *(const uint4*)v;
    }
    {
      const u16* wsrc = Wt + (size_t)kb * 4096;
#pragma unroll
      for (int j = 0; j < 2; ++j) {
        int chunk = tid * 2 + j;
        int rowb = chunk >> 2, kk = (chunk & 3) << 3;
        *(uint4*)&Bsh[rowb * 40 + kk] = *(const uint4*)(wsrc + chunk * 8);
      }
    }
    __syncthreads();
    {
      const int rl = lane & 15, kq = lane >> 4;
      short8 af = *(const short8*)&Ash[(w * 16 + rl) * 40 + kq * 8];
#pragma unroll
      for (int t = 0; t < 8; ++t) {
        short8 bf = *(const short8*)&Bsh[(t * 16 + rl) * 40 + kq * 8];
        acc[t] = __builtin_amdgcn_mfma_f32_16x16x32_bf16(
            __builtin_bit_cast(bf16x8, af), __builtin_bit_cast(bf16x8, bf), acc[t], 0, 0, 0);
      }
    }
    __syncthreads();
  }
  // epilogue: C/D layout col=lane&15, row=(lane>>4)*4+i
  const int rl = lane & 15, rq = lane >> 4;
#pragma unroll
  for (int i = 0; i < 4; ++i) {
    int grow = row0 + w * 16 + rq * 4 + i;
    if (grow < M) {
      float dv = (EPI == 0) ? dinv[grow] : 0.f;
#pragma unroll
      for (int t = 0; t < 8; ++t) {
        int col = t * 16 + rl;
        if (EPI == 0) {
          gout[(size_t)grow * HID + col] = f2bf(dv * acc[t][i]);   // h' = dinv * (A@W)
        } else {
          float vv = acc[t][i] + bias[col];
          fout[(size_t)grow * HID + col] = 1.0f / (1.0f + __expf(-vv));
        }
      }
    }
  }
}

// ---------------- aggregation: out[d] = bias + dinv[d]*(2*h'[d] + sum h'[s]) ----------------
// one wave per dst node, 4 groups x 16 lanes, unroll x4 (16 gathers in flight per wave)
template<int RELU>
__global__ __launch_bounds__(256) void k_agg(const u16* __restrict__ h, u16* __restrict__ g,
                                             const float* __restrict__ bias, const float* __restrict__ dinv,
                                             const int* __restrict__ off, const int* __restrict__ edges,
                                             int n) {
  int wave = blockIdx.x * 4 + (threadIdx.x >> 6);
  int lane = threadIdx.x & 63;
  if (wave >= n) return;
  const int d  = wave;
  const int gr = lane >> 4;
  const int t  = lane & 15;
  const int c  = t << 3;
  float a[8];
#pragma unroll
  for (int i = 0; i < 8; ++i) a[i] = 0.f;

  int j  = off[d] + gr;
  const int j1 = off[d + 1];
  for (; j + 12 < j1; j += 16) {
    int s0 = edges[j], s1 = edges[j + 4], s2 = edges[j + 8], s3 = edges[j + 12];
    uint4 v0 = *(const uint4*)(h + (size_t)s0 * HID + c);
    uint4 v1 = *(const uint4*)(h + (size_t)s1 * HID + c);
    uint4 v2 = *(const uint4*)(h + (size_t)s2 * HID + c);
    uint4 v3 = *(const uint4*)(h + (size_t)s3 * HID + c);
    add8(a, v0); add8(a, v1); add8(a, v2); add8(a, v3);
  }
  for (; j + 4 < j1; j += 8) {
    int s0 = edges[j], s1 = edges[j + 4];
    uint4 v0 = *(const uint4*)(h + (size_t)s0 * HID + c);
    uint4 v1 = *(const uint4*)(h + (size_t)s1 * HID + c);
    add8(a, v0); add8(a, v1);
  }
  for (; j < j1; j += 4) {
    uint4 v0 = *(const uint4*)(h + (size_t)edges[j] * HID + c);
    add8(a, v0);
  }
#pragma unroll
  for (int i = 0; i < 8; ++i) {
    a[i] += __shfl_xor(a[i], 16);
    a[i] += __shfl_xor(a[i], 32);
  }
  float di = dinv[d];
  uint4 sv = *(const uint4*)(h + (size_t)d * HID + c);    // h'[d]
  const float4 bv0 = *(const float4*)(bias + c);
  const float4 bv1 = *(const float4*)(bias + c + 4);
  a[0] = bv0.x + di * (a[0] + 2.f * bflo(sv.x));
  a[1] = bv0.y + di * (a[1] + 2.f * bfhi(sv.x));
  a[2] = bv0.z + di * (a[2] + 2.f * bflo(sv.y));
  a[3] = bv0.w + di * (a[3] + 2.f * bfhi(sv.y));
  a[4] = bv1.x + di * (a[4] + 2.f * bflo(sv.z));
  a[5] = bv1.y + di * (a[5] + 2.f * bfhi(sv.z));
  a[6] = bv1.z + di * (a[6] + 2.f * bflo(sv.w));
  a[7] = bv1.w + di * (a[7] + 2.f * bfhi(sv.w));
  if (RELU) {
#pragma unroll
    for (int i = 0; i < 8; ++i) a[i] = fmaxf(a[i], 0.f);
  }
  if (gr == 0) {
    uint4 o;
    o.x = (uint32_t)f2bf(a[0]) | ((uint32_t)f2bf(a[1]) << 16);
    o.y = (uint32_t)f2bf(a[2]) | ((uint32_t)f2bf(a[3]) << 16);
    o.z = (uint32_t)f2bf(a[4]) | ((uint32_t)f2bf(a[5]) << 16);
    o.w = (uint32_t)f2bf(a[6]) | ((uint32_t)f2bf(a[7]) << 16);
    *(uint4*)(g + (size_t)d * HID + c) = o;
  }
}

extern "C" void kernel_launch(void* const* d_in, const int* in_sizes, int n_in,
                              void* d_out, int out_size, void* d_ws, size_t ws_size,
                              hipStream_t stream) {
  const float* x   = (const float*)d_in[0];
  const int*   ei  = (const int*)d_in[1];        // [2, E] int32
  const float* W1  = (const float*)d_in[2];
  const float* b1  = (const float*)d_in[3];
  const float* W2  = (const float*)d_in[4];
  const float* b2  = (const float*)d_in[5];
  const float* We  = (const float*)d_in[6];
  const float* be  = (const float*)d_in[7];
  const float* Wf  = (const float*)d_in[8];
  const float* bfv = (const float*)d_in[9];
  float* out = (float*)d_out;

  const int* src = ei;
  const int* dst = ei + EE;

  char* p = (char*)d_ws;
  auto take = [&](size_t bytes) { char* r = p; p += (bytes + 255) & ~(size_t)255; return r; };
  int*   bcnt  = (int*)take((size_t)NBUCK * 4);
  int*   boff  = (int*)take((size_t)(NBUCK + 1) * 4);
  int*   bcur  = (int*)take((size_t)NBUCK * 4);
  int*   off   = (int*)take((size_t)(NN + 1) * 4);
  float* dinv  = (float*)take((size_t)NN * 4);
  int*   edges = (int*)take((size_t)EE * 4);
  u16*   hA    = (u16*)take((size_t)NN * HID * 2);
  u16*   hB    = (u16*)take((size_t)NN * HID * 2);
  u16*   Wt1   = (u16*)take((size_t)FIN * HID * 2);
  u16*   Wt2   = (u16*)take((size_t)HID * HID * 2);
  u16*   Wt3   = (u16*)take((size_t)HID * HID * 2);
  u16*   Wt4   = (u16*)take((size_t)HID * HID * 2);
  // ebuck (3.2MB) aliases hB (12.8MB): ebuck is dead before agg1 writes hB.
  int*   ebuck = (int*)hB;

  // bucketed CSR build
  hipMemsetAsync(bcnt, 0, (size_t)NBUCK * 4, stream);
  k_bhist<<<NCBLK, 256, 0, stream>>>(dst, bcnt, EE);
  k_bscan<<<1, 256, 0, stream>>>(bcnt, boff, bcur, off);
  k_bscatter<<<NCBLK, 256, 0, stream>>>(src, dst, bcur, ebuck, EE);
  k_ncount<<<NBUCK, 256, 0, stream>>>(ebuck, boff, off, dinv);
  k_fill2<<<NBUCK, 256, 0, stream>>>(ebuck, boff, off, edges);

  // weights -> tiled bf16 (single launch)
  k_wconv_all<<<(81920 + 255) / 256, 256, 0, stream>>>(W1, W2, We, Wf, Wt1, Wt2, Wt3, Wt4);

  const int gemm_grid = (NN + 63) / 64;
  const int agg_grid  = (NN + 3) / 4;

  // layer 1: h' = dinv*(x@W1) ; g = relu(b1 + dinv*(2h'[d] + sum h'[s]))
  k_gemm<1, 0><<<gemm_grid, 256, 0, stream>>>(x, nullptr, Wt1, nullptr, dinv, hA, nullptr, NN, FIN);
  k_agg<1><<<agg_grid, 256, 0, stream>>>(hA, hB, b1, dinv, off, edges, NN);
  // layer 2
  k_gemm<0, 0><<<gemm_grid, 256, 0, stream>>>(nullptr, hB, Wt2, nullptr, dinv, hA, nullptr, NN, HID);
  k_agg<1><<<agg_grid, 256, 0, stream>>>(hA, hB, b2, dinv, off, edges, NN);
  // layer 3 (no relu)
  k_gemm<0, 0><<<gemm_grid, 256, 0, stream>>>(nullptr, hB, Wt3, nullptr, dinv, hA, nullptr, NN, HID);
  k_agg<0><<<agg_grid, 256, 0, stream>>>(hA, hB, be, dinv, off, edges, NN);
  // final dense + sigmoid
  k_gemm<0, 1><<<gemm_grid, 256, 0, stream>>>(nullptr, hB, Wt4, bfv, dinv, nullptr, out, NN, HID);
}